// Round 2
// baseline (451.670 us; speedup 1.0000x reference)
//
#include <hip/hip_runtime.h>
#include <hip/hip_bf16.h>
#include <math.h>

#define B_ 4
#define T_ 2048
#define DM 768
#define H_ 12
#define DH 64

typedef __attribute__((ext_vector_type(4))) float f32x4;
typedef __attribute__((ext_vector_type(8))) short s16x8;

typedef const __attribute__((address_space(1))) void* gas1_t;
typedef __attribute__((address_space(3))) void* las3_t;

__device__ __forceinline__ ushort f2b(float f) {
  union { float f; unsigned u; } v; v.f = f;
  unsigned u = v.u;
  u += 0x7fffu + ((u >> 16) & 1u);
  return (ushort)(u >> 16);
}
__device__ __forceinline__ float b2f(ushort b) {
  union { unsigned u; float f; } v; v.u = ((unsigned)b) << 16;
  return v.f;
}

// ---------------- fused fp32->bf16 conversions + rope pack, one launch ----------------
// blocks [0,6144): x -> xb ; [6144,8448): weights -> wqkv/wob ; [8448,8704): cos/sin pack
__global__ void cvt_all(const float* __restrict__ x,
                        const float* __restrict__ wq, const float* __restrict__ wk,
                        const float* __restrict__ wv, const float* __restrict__ wo,
                        const float* __restrict__ rc, const float* __restrict__ rs,
                        ushort* __restrict__ xb, ushort* __restrict__ wqkv,
                        ushort* __restrict__ wob, float2* __restrict__ cs2) {
  const int bid = blockIdx.x, t = threadIdx.x;
  if (bid < 6144) {
    int i = bid * 256 + t;
    float4 v = ((const float4*)x)[i];
    ushort4 o;
    o.x = f2b(v.x); o.y = f2b(v.y); o.z = f2b(v.z); o.w = f2b(v.w);
    ((ushort4*)xb)[i] = o;
  } else if (bid < 8448) {
    int i = (bid - 6144) * 256 + t;  // 0 .. 589823
    int which = i / 147456, j = i - which * 147456;
    const float* src = which == 0 ? wq : which == 1 ? wk : which == 2 ? wv : wo;
    ushort* dst = which < 3 ? wqkv + (size_t)which * 589824 : wob;
    float4 v = ((const float4*)src)[j];
    ushort4 o;
    o.x = f2b(v.x); o.y = f2b(v.y); o.z = f2b(v.z); o.w = f2b(v.w);
    ((ushort4*)dst)[j] = o;
  } else {
    int i = (bid - 8448) * 256 + t;  // 0 .. 65535
    cs2[i] = make_float2(rc[i], rs[i]);
  }
}

// ---------------- QKV GEMM, BK=64: 32 MFMA per barrier pair ----------------
// LDS staged via global_load_lds with pre-swizzled global source (colblock
// cb ^ (row&7)); frag reads XOR the same involution -> conflict-free b128.
__global__ __launch_bounds__(256, 3) void gemm_qkv(
    const ushort* __restrict__ A, const ushort* __restrict__ Bw,
    const float2* __restrict__ cs2,
    ushort* __restrict__ Qb, ushort* __restrict__ Kb, ushort* __restrict__ Vt) {
  const int K = 768;
  __shared__ ushort As[128 * 64];
  __shared__ ushort Bs[128 * 64];
  const int m0 = blockIdx.y * 128, n0 = blockIdx.x * 128;
  const int tid = threadIdx.x;
  const int wave = tid >> 6, lane = tid & 63;
  const int wm = (wave >> 1) * 64, wn = (wave & 1) * 64;
  const int quad = lane >> 4, l16 = lane & 15;
  const int tr = tid >> 3;                 // staging row 0..31 (per 32-row pass)
  const int scb = (tid & 7) ^ (tr & 7);    // pre-swizzled source colblock
  const int swz = l16 & 7;                 // frag-read swizzle term (= row&7)

  f32x4 acc[4][4] = {};

  const ushort* ga = A + (size_t)(m0 + tr) * K + scb * 8;
  const ushort* gb = Bw + (size_t)(n0 + tr) * K + scb * 8;

  for (int k0 = 0; k0 < K; k0 += 64) {
#pragma unroll
    for (int p = 0; p < 4; p++) {
      __builtin_amdgcn_global_load_lds((gas1_t)(ga + (size_t)(p * 32) * K + k0),
                                       (las3_t)(As + p * 2048 + tid * 8), 16, 0, 0);
      __builtin_amdgcn_global_load_lds((gas1_t)(gb + (size_t)(p * 32) * K + k0),
                                       (las3_t)(Bs + p * 2048 + tid * 8), 16, 0, 0);
    }
    __syncthreads();
#pragma unroll
    for (int kk = 0; kk < 2; kk++) {
      s16x8 af[4], bf[4];
#pragma unroll
      for (int i = 0; i < 4; i++) {
        const ushort* ar = As + (wm + i * 16 + l16) * 64;
        af[i] = *(const s16x8*)(ar + (((kk * 4 + quad) ^ swz) * 8));
        const ushort* br = Bs + (wn + i * 16 + l16) * 64;
        bf[i] = *(const s16x8*)(br + (((kk * 4 + quad) ^ swz) * 8));
      }
#pragma unroll
      for (int i = 0; i < 4; i++)
#pragma unroll
        for (int n = 0; n < 4; n++)
          acc[i][n] = __builtin_amdgcn_mfma_f32_16x16x32_bf16(af[i], bf[n], acc[i][n], 0, 0, 0);
    }
    __syncthreads();
  }

  const int sec = n0 / 768;  // 0=q, 1=k, 2=v (uniform per block)
  if (sec < 2) {
    ushort* dst = sec == 0 ? Qb : Kb;
#pragma unroll
    for (int i = 0; i < 4; i++) {
      int row0 = m0 + wm + i * 16 + quad * 4;
#pragma unroll
      for (int nt = 0; nt < 4; nt++) {
        int col = n0 + wn + nt * 16 + l16;
        int nn = col - sec * 768;
        int h = nn >> 6, d = nn & 63;
        int ip = (d >> 1) & 31;
        float sgn = (d & 1) ? 1.f : -1.f;
#pragma unroll
        for (int r = 0; r < 4; r++) {
          int rrow = row0 + r;
          int t = rrow & (T_ - 1), bb = rrow >> 11;
          float v = acc[i][nt][r];
          float partner = __shfl_xor(v, 1);
          float2 cs = cs2[t * 32 + ip];
          float out = fmaf(v, cs.x, sgn * partner * cs.y);
          dst[((size_t)(bb * H_ + h) * T_ + t) * DH + d] = f2b(out);
        }
      }
    }
  } else {
#pragma unroll
    for (int i = 0; i < 4; i++) {
      int row0 = m0 + wm + i * 16 + quad * 4;
      int t0 = row0 & (T_ - 1), b = row0 >> 11;  // 4 rows share b (aligned)
#pragma unroll
      for (int nt = 0; nt < 4; nt++) {
        int col = n0 + wn + nt * 16 + l16;
        int nn = col - 1536;
        int h = nn >> 6, d = nn & 63;
        ushort4 pk;
        pk.x = f2b(acc[i][nt][0]); pk.y = f2b(acc[i][nt][1]);
        pk.z = f2b(acc[i][nt][2]); pk.w = f2b(acc[i][nt][3]);
        *(ushort4*)(Vt + ((size_t)(b * H_ + h) * DH + d) * T_ + t0) = pk;
      }
    }
  }
}

// ---------------- output GEMM: 128x128 tiles, BK=64 ----------------
__global__ __launch_bounds__(256, 3) void gemm_out(
    const ushort* __restrict__ A, const ushort* __restrict__ Bw, float* __restrict__ C) {
  const int K = 768, N = 768;
  __shared__ ushort As[128 * 64];
  __shared__ ushort Bs[128 * 64];
  const int m0 = blockIdx.y * 128, n0 = blockIdx.x * 128;
  const int tid = threadIdx.x;
  const int wave = tid >> 6, lane = tid & 63;
  const int wm = (wave >> 1) * 64, wn = (wave & 1) * 64;
  const int quad = lane >> 4, l16 = lane & 15;
  const int tr = tid >> 3;
  const int scb = (tid & 7) ^ (tr & 7);
  const int swz = l16 & 7;

  f32x4 acc[4][4] = {};

  const ushort* ga = A + (size_t)(m0 + tr) * K + scb * 8;
  const ushort* gb = Bw + (size_t)(n0 + tr) * K + scb * 8;

  for (int k0 = 0; k0 < K; k0 += 64) {
#pragma unroll
    for (int p = 0; p < 4; p++) {
      __builtin_amdgcn_global_load_lds((gas1_t)(ga + (size_t)(p * 32) * K + k0),
                                       (las3_t)(As + p * 2048 + tid * 8), 16, 0, 0);
      __builtin_amdgcn_global_load_lds((gas1_t)(gb + (size_t)(p * 32) * K + k0),
                                       (las3_t)(Bs + p * 2048 + tid * 8), 16, 0, 0);
    }
    __syncthreads();
#pragma unroll
    for (int kk = 0; kk < 2; kk++) {
      s16x8 af[4], bf[4];
#pragma unroll
      for (int i = 0; i < 4; i++) {
        const ushort* ar = As + (wm + i * 16 + l16) * 64;
        af[i] = *(const s16x8*)(ar + (((kk * 4 + quad) ^ swz) * 8));
        const ushort* br = Bs + (wn + i * 16 + l16) * 64;
        bf[i] = *(const s16x8*)(br + (((kk * 4 + quad) ^ swz) * 8));
      }
#pragma unroll
      for (int i = 0; i < 4; i++)
#pragma unroll
        for (int n = 0; n < 4; n++)
          acc[i][n] = __builtin_amdgcn_mfma_f32_16x16x32_bf16(af[i], bf[n], acc[i][n], 0, 0, 0);
    }
    __syncthreads();
  }

#pragma unroll
  for (int i = 0; i < 4; i++) {
    int row = m0 + wm + i * 16 + quad * 4;
#pragma unroll
    for (int n = 0; n < 4; n++) {
      int col = n0 + wn + n * 16 + l16;
#pragma unroll
      for (int r = 0; r < 4; r++)
        C[(size_t)(row + r) * N + col] = acc[i][n][r];
    }
  }
}

// ---------------- causal flash attention v8: 4 blocks/CU + setprio ----------------
// Balanced pairing (tile p with tile 31-p). P shrunk to pitch-64 with XOR slot
// swizzle (col ^ ((row&7)<<3), same involution on write and read) -> LDS
// 40960 B = exactly 4 blocks/CU.
#define EXP2SCALE 0.18033688f   /* 0.125 * log2(e) */
#define EXP2OFF  17.312340f     /* 12 * log2(e) */
__global__ __launch_bounds__(256, 4) void attn(const ushort* __restrict__ Qb, const ushort* __restrict__ Kb,
                                               const ushort* __restrict__ Vt, ushort* __restrict__ Ob) {
  const int bh = blockIdx.x;
  const int p = blockIdx.y;        // pair index 0..15
  const int tid = threadIdx.x, wave = tid >> 6, lane = tid & 63;
  const int quad = lane >> 4, l16 = lane & 15;
  const int b = bh / H_, h = bh % H_;
  const ushort* Qp = Qb + (size_t)bh * T_ * DH;
  const ushort* Kp = Kb + (size_t)bh * T_ * DH;
  const ushort* Vp = Vt + (size_t)bh * DH * T_;

  __shared__ ushort Ks[2][64 * 64];
  __shared__ ushort Vs[2][64 * 64];
  __shared__ ushort P[4][16][64];   // per wave; XOR slot-swizzled

  const int myTile = (wave < 2) ? p : (31 - p);     // 64-row q tile
  const int qbase0 = myTile * 64 + (wave & 1) * 32; // this wave's 32 rows

  s16x8 aq[2][2];
#pragma unroll
  for (int m = 0; m < 2; m++) {
    const ushort* qp = Qp + (size_t)(qbase0 + m * 16 + l16) * DH + quad * 8;
    aq[m][0] = *(const s16x8*)qp;
    aq[m][1] = *(const s16x8*)(qp + 32);
  }
  f32x4 o[2][4] = {};
  float rsum[2][4] = {{0.f, 0.f, 0.f, 0.f}, {0.f, 0.f, 0.f, 0.f}};

  const int ntile = 32 - p;  // kv tiles 0..31-p cover tile 31-p; tile p subsets
  const int srow = tid >> 3;                   // 0..31
  const int scbK = (tid & 7) ^ (srow & 7);     // swizzled source colblock
  const int swz = (l16 & 7);

  {
    const int kv0 = 0;
    __builtin_amdgcn_global_load_lds((gas1_t)(Kp + (size_t)(kv0 + srow) * DH + scbK * 8),
                                     (las3_t)(Ks[0] + tid * 8), 16, 0, 0);
    __builtin_amdgcn_global_load_lds((gas1_t)(Kp + (size_t)(kv0 + srow + 32) * DH + scbK * 8),
                                     (las3_t)(Ks[0] + 2048 + tid * 8), 16, 0, 0);
    __builtin_amdgcn_global_load_lds((gas1_t)(Vp + (size_t)srow * T_ + kv0 + scbK * 8),
                                     (las3_t)(Vs[0] + tid * 8), 16, 0, 0);
    __builtin_amdgcn_global_load_lds((gas1_t)(Vp + (size_t)(srow + 32) * T_ + kv0 + scbK * 8),
                                     (las3_t)(Vs[0] + 2048 + tid * 8), 16, 0, 0);
  }

  for (int c = 0; c < ntile; c++) {
    const int kv0 = c * 64;
    const int cur = c & 1;
    __syncthreads();  // drains own vmcnt -> buf[cur] staged & visible
    if (c + 1 < ntile) {
      const int kv1 = kv0 + 64, nxt = cur ^ 1;
      __builtin_amdgcn_global_load_lds((gas1_t)(Kp + (size_t)(kv1 + srow) * DH + scbK * 8),
                                       (las3_t)(Ks[nxt] + tid * 8), 16, 0, 0);
      __builtin_amdgcn_global_load_lds((gas1_t)(Kp + (size_t)(kv1 + srow + 32) * DH + scbK * 8),
                                       (las3_t)(Ks[nxt] + 2048 + tid * 8), 16, 0, 0);
      __builtin_amdgcn_global_load_lds((gas1_t)(Vp + (size_t)srow * T_ + kv1 + scbK * 8),
                                       (las3_t)(Vs[nxt] + tid * 8), 16, 0, 0);
      __builtin_amdgcn_global_load_lds((gas1_t)(Vp + (size_t)(srow + 32) * T_ + kv1 + scbK * 8),
                                       (las3_t)(Vs[nxt] + 2048 + tid * 8), 16, 0, 0);
    }

    // wave-uniform: skip frag reads + compute entirely once past this wave's diagonal
    if (kv0 <= qbase0 + 31) {
      s16x8 kf[4][2];
#pragma unroll
      for (int nt = 0; nt < 4; nt++) {
        const ushort* kr = Ks[cur] + (nt * 16 + l16) * 64;
        kf[nt][0] = *(const s16x8*)(kr + ((quad ^ swz) * 8));
        kf[nt][1] = *(const s16x8*)(kr + (((4 + quad) ^ swz) * 8));
      }
      s16x8 bv[4][2];
#pragma unroll
      for (int dt = 0; dt < 4; dt++) {
        const ushort* vr = Vs[cur] + (dt * 16 + l16) * 64;
        bv[dt][0] = *(const s16x8*)(vr + ((quad ^ swz) * 8));
        bv[dt][1] = *(const s16x8*)(vr + (((4 + quad) ^ swz) * 8));
      }

#pragma unroll
      for (int m = 0; m < 2; m++) {
        const int qb = qbase0 + m * 16;
        if (kv0 > qb + 15) continue;  // fully masked frag (wave-uniform)
        f32x4 s[4] = {};
        __builtin_amdgcn_s_setprio(1);
#pragma unroll
        for (int nt = 0; nt < 4; nt++) {
          s[nt] = __builtin_amdgcn_mfma_f32_16x16x32_bf16(aq[m][0], kf[nt][0], s[nt], 0, 0, 0);
          s[nt] = __builtin_amdgcn_mfma_f32_16x16x32_bf16(aq[m][1], kf[nt][1], s[nt], 0, 0, 0);
        }
        __builtin_amdgcn_s_setprio(0);
        if (kv0 + 63 <= qb) {  // fully unmasked
#pragma unroll
          for (int nt = 0; nt < 4; nt++)
#pragma unroll
            for (int r = 0; r < 4; r++) {
              float pv = __builtin_amdgcn_exp2f(fmaf(s[nt][r], EXP2SCALE, -EXP2OFF));
              rsum[m][r] += pv;
              int row = quad * 4 + r;
              P[wave][row][(nt * 16 + l16) ^ ((row & 7) << 3)] = f2b(pv);
            }
        } else {  // diagonal tile
#pragma unroll
          for (int nt = 0; nt < 4; nt++) {
            int kv = kv0 + nt * 16 + l16;
#pragma unroll
            for (int r = 0; r < 4; r++) {
              int qi = qb + quad * 4 + r;
              float pv = (kv <= qi) ? __builtin_amdgcn_exp2f(fmaf(s[nt][r], EXP2SCALE, -EXP2OFF)) : 0.f;
              rsum[m][r] += pv;
              int row = quad * 4 + r;
              P[wave][row][(nt * 16 + l16) ^ ((row & 7) << 3)] = f2b(pv);
            }
          }
        }
        s16x8 ap0 = *(const s16x8*)&P[wave][l16][((0 + quad) ^ swz) * 8];
        s16x8 ap1 = *(const s16x8*)&P[wave][l16][((4 + quad) ^ swz) * 8];
        __builtin_amdgcn_s_setprio(1);
#pragma unroll
        for (int dt = 0; dt < 4; dt++) {
          o[m][dt] = __builtin_amdgcn_mfma_f32_16x16x32_bf16(ap0, bv[dt][0], o[m][dt], 0, 0, 0);
          o[m][dt] = __builtin_amdgcn_mfma_f32_16x16x32_bf16(ap1, bv[dt][1], o[m][dt], 0, 0, 0);
        }
        __builtin_amdgcn_s_setprio(0);
      }
    }
  }
#pragma unroll
  for (int off = 1; off < 16; off <<= 1)
#pragma unroll
    for (int m = 0; m < 2; m++)
#pragma unroll
      for (int r = 0; r < 4; r++)
        rsum[m][r] += __shfl_xor(rsum[m][r], off);
#pragma unroll
  for (int m = 0; m < 2; m++)
#pragma unroll
    for (int dt = 0; dt < 4; dt++)
#pragma unroll
      for (int r = 0; r < 4; r++) {
        int q = qbase0 + m * 16 + quad * 4 + r;
        Ob[(size_t)(b * T_ + q) * DM + h * 64 + dt * 16 + l16] = f2b(o[m][dt][r] / rsum[m][r]);
      }
}

extern "C" void kernel_launch(void* const* d_in, const int* in_sizes, int n_in,
                              void* d_out, int out_size, void* d_ws, size_t ws_size,
                              hipStream_t stream) {
  const float* x = (const float*)d_in[0];
  const float* rc = (const float*)d_in[1];
  const float* rs = (const float*)d_in[2];
  const float* wq = (const float*)d_in[3];
  const float* wk = (const float*)d_in[4];
  const float* wv = (const float*)d_in[5];
  const float* wo = (const float*)d_in[6];

  char* ws = (char*)d_ws;
  ushort* xb   = (ushort*)(ws);                 // 12,582,912
  ushort* wqkv = (ushort*)(ws + 12582912);      //  3,538,944
  ushort* wob  = (ushort*)(ws + 16121856);      //  1,179,648
  float2* cs2  = (float2*)(ws + 17301504);      //    524,288
  ushort* Qb   = (ushort*)(ws + 17825792);      // 12,582,912
  ushort* Kb   = (ushort*)(ws + 30408704);      // 12,582,912
  ushort* Vt   = (ushort*)(ws + 42991616);      // 12,582,912
  ushort* Ob   = (ushort*)(ws + 55574528);      // 12,582,912 (ends ~68.2MB)

  cvt_all<<<8704, 256, 0, stream>>>(x, wq, wk, wv, wo, rc, rs, xb, wqkv, wob, cs2);

  gemm_qkv<<<dim3(18, 64), 256, 0, stream>>>(xb, wqkv, cs2, Qb, Kb, Vt);

  attn<<<dim3(48, 16), 256, 0, stream>>>(Qb, Kb, Vt, Ob);

  gemm_out<<<dim3(6, 64), 256, 0, stream>>>(Ob, wob, (float*)d_out);
}

// Round 3
// 232.870 us; speedup vs baseline: 1.9396x; 1.9396x over previous
//
#include <hip/hip_runtime.h>
#include <hip/hip_bf16.h>
#include <math.h>

#define B_ 4
#define T_ 2048
#define DM 768
#define H_ 12
#define DH 64

typedef __attribute__((ext_vector_type(4))) float f32x4;
typedef __attribute__((ext_vector_type(8))) short s16x8;

typedef const __attribute__((address_space(1))) void* gas1_t;
typedef __attribute__((address_space(3))) void* las3_t;

__device__ __forceinline__ ushort f2b(float f) {
  union { float f; unsigned u; } v; v.f = f;
  unsigned u = v.u;
  u += 0x7fffu + ((u >> 16) & 1u);
  return (ushort)(u >> 16);
}
__device__ __forceinline__ float b2f(ushort b) {
  union { unsigned u; float f; } v; v.u = ((unsigned)b) << 16;
  return v.f;
}

// ---------------- fused fp32->bf16 conversions + rope pack, one launch ----------------
// blocks [0,6144): x -> xb ; [6144,8448): weights -> wqkv/wob ; [8448,8704): cos/sin pack
__global__ void cvt_all(const float* __restrict__ x,
                        const float* __restrict__ wq, const float* __restrict__ wk,
                        const float* __restrict__ wv, const float* __restrict__ wo,
                        const float* __restrict__ rc, const float* __restrict__ rs,
                        ushort* __restrict__ xb, ushort* __restrict__ wqkv,
                        ushort* __restrict__ wob, float2* __restrict__ cs2) {
  const int bid = blockIdx.x, t = threadIdx.x;
  if (bid < 6144) {
    int i = bid * 256 + t;
    float4 v = ((const float4*)x)[i];
    ushort4 o;
    o.x = f2b(v.x); o.y = f2b(v.y); o.z = f2b(v.z); o.w = f2b(v.w);
    ((ushort4*)xb)[i] = o;
  } else if (bid < 8448) {
    int i = (bid - 6144) * 256 + t;  // 0 .. 589823
    int which = i / 147456, j = i - which * 147456;
    const float* src = which == 0 ? wq : which == 1 ? wk : which == 2 ? wv : wo;
    ushort* dst = which < 3 ? wqkv + (size_t)which * 589824 : wob;
    float4 v = ((const float4*)src)[j];
    ushort4 o;
    o.x = f2b(v.x); o.y = f2b(v.y); o.z = f2b(v.z); o.w = f2b(v.w);
    ((ushort4*)dst)[j] = o;
  } else {
    int i = (bid - 8448) * 256 + t;  // 0 .. 65535
    cs2[i] = make_float2(rc[i], rs[i]);
  }
}

// ---------------- QKV GEMM, BK=64: 32 MFMA per barrier pair ----------------
// LDS staged via global_load_lds with pre-swizzled global source (colblock
// cb ^ (row&7)); frag reads XOR the same involution -> conflict-free b128.
__global__ __launch_bounds__(256, 3) void gemm_qkv(
    const ushort* __restrict__ A, const ushort* __restrict__ Bw,
    const float2* __restrict__ cs2,
    ushort* __restrict__ Qb, ushort* __restrict__ Kb, ushort* __restrict__ Vt) {
  const int K = 768;
  __shared__ ushort As[128 * 64];
  __shared__ ushort Bs[128 * 64];
  const int m0 = blockIdx.y * 128, n0 = blockIdx.x * 128;
  const int tid = threadIdx.x;
  const int wave = tid >> 6, lane = tid & 63;
  const int wm = (wave >> 1) * 64, wn = (wave & 1) * 64;
  const int quad = lane >> 4, l16 = lane & 15;
  const int tr = tid >> 3;                 // staging row 0..31 (per 32-row pass)
  const int scb = (tid & 7) ^ (tr & 7);    // pre-swizzled source colblock
  const int swz = l16 & 7;                 // frag-read swizzle term (= row&7)

  f32x4 acc[4][4] = {};

  const ushort* ga = A + (size_t)(m0 + tr) * K + scb * 8;
  const ushort* gb = Bw + (size_t)(n0 + tr) * K + scb * 8;

  for (int k0 = 0; k0 < K; k0 += 64) {
#pragma unroll
    for (int p = 0; p < 4; p++) {
      __builtin_amdgcn_global_load_lds((gas1_t)(ga + (size_t)(p * 32) * K + k0),
                                       (las3_t)(As + p * 2048 + tid * 8), 16, 0, 0);
      __builtin_amdgcn_global_load_lds((gas1_t)(gb + (size_t)(p * 32) * K + k0),
                                       (las3_t)(Bs + p * 2048 + tid * 8), 16, 0, 0);
    }
    __syncthreads();
#pragma unroll
    for (int kk = 0; kk < 2; kk++) {
      s16x8 af[4], bf[4];
#pragma unroll
      for (int i = 0; i < 4; i++) {
        const ushort* ar = As + (wm + i * 16 + l16) * 64;
        af[i] = *(const s16x8*)(ar + (((kk * 4 + quad) ^ swz) * 8));
        const ushort* br = Bs + (wn + i * 16 + l16) * 64;
        bf[i] = *(const s16x8*)(br + (((kk * 4 + quad) ^ swz) * 8));
      }
#pragma unroll
      for (int i = 0; i < 4; i++)
#pragma unroll
        for (int n = 0; n < 4; n++)
          acc[i][n] = __builtin_amdgcn_mfma_f32_16x16x32_bf16(af[i], bf[n], acc[i][n], 0, 0, 0);
    }
    __syncthreads();
  }

  const int sec = n0 / 768;  // 0=q, 1=k, 2=v (uniform per block)
  if (sec < 2) {
    ushort* dst = sec == 0 ? Qb : Kb;
#pragma unroll
    for (int i = 0; i < 4; i++) {
      int row0 = m0 + wm + i * 16 + quad * 4;
#pragma unroll
      for (int nt = 0; nt < 4; nt++) {
        int col = n0 + wn + nt * 16 + l16;
        int nn = col - sec * 768;
        int h = nn >> 6, d = nn & 63;
        int ip = (d >> 1) & 31;
        float sgn = (d & 1) ? 1.f : -1.f;
#pragma unroll
        for (int r = 0; r < 4; r++) {
          int rrow = row0 + r;
          int t = rrow & (T_ - 1), bb = rrow >> 11;
          float v = acc[i][nt][r];
          float partner = __shfl_xor(v, 1);
          float2 cs = cs2[t * 32 + ip];
          float out = fmaf(v, cs.x, sgn * partner * cs.y);
          dst[((size_t)(bb * H_ + h) * T_ + t) * DH + d] = f2b(out);
        }
      }
    }
  } else {
#pragma unroll
    for (int i = 0; i < 4; i++) {
      int row0 = m0 + wm + i * 16 + quad * 4;
      int t0 = row0 & (T_ - 1), b = row0 >> 11;  // 4 rows share b (aligned)
#pragma unroll
      for (int nt = 0; nt < 4; nt++) {
        int col = n0 + wn + nt * 16 + l16;
        int nn = col - 1536;
        int h = nn >> 6, d = nn & 63;
        ushort4 pk;
        pk.x = f2b(acc[i][nt][0]); pk.y = f2b(acc[i][nt][1]);
        pk.z = f2b(acc[i][nt][2]); pk.w = f2b(acc[i][nt][3]);
        *(ushort4*)(Vt + ((size_t)(b * H_ + h) * DH + d) * T_ + t0) = pk;
      }
    }
  }
}

// ---------------- output GEMM: 128x128 tiles, BK=64 ----------------
__global__ __launch_bounds__(256, 3) void gemm_out(
    const ushort* __restrict__ A, const ushort* __restrict__ Bw, float* __restrict__ C) {
  const int K = 768, N = 768;
  __shared__ ushort As[128 * 64];
  __shared__ ushort Bs[128 * 64];
  const int m0 = blockIdx.y * 128, n0 = blockIdx.x * 128;
  const int tid = threadIdx.x;
  const int wave = tid >> 6, lane = tid & 63;
  const int wm = (wave >> 1) * 64, wn = (wave & 1) * 64;
  const int quad = lane >> 4, l16 = lane & 15;
  const int tr = tid >> 3;
  const int scb = (tid & 7) ^ (tr & 7);
  const int swz = l16 & 7;

  f32x4 acc[4][4] = {};

  const ushort* ga = A + (size_t)(m0 + tr) * K + scb * 8;
  const ushort* gb = Bw + (size_t)(n0 + tr) * K + scb * 8;

  for (int k0 = 0; k0 < K; k0 += 64) {
#pragma unroll
    for (int p = 0; p < 4; p++) {
      __builtin_amdgcn_global_load_lds((gas1_t)(ga + (size_t)(p * 32) * K + k0),
                                       (las3_t)(As + p * 2048 + tid * 8), 16, 0, 0);
      __builtin_amdgcn_global_load_lds((gas1_t)(gb + (size_t)(p * 32) * K + k0),
                                       (las3_t)(Bs + p * 2048 + tid * 8), 16, 0, 0);
    }
    __syncthreads();
#pragma unroll
    for (int kk = 0; kk < 2; kk++) {
      s16x8 af[4], bf[4];
#pragma unroll
      for (int i = 0; i < 4; i++) {
        const ushort* ar = As + (wm + i * 16 + l16) * 64;
        af[i] = *(const s16x8*)(ar + (((kk * 4 + quad) ^ swz) * 8));
        const ushort* br = Bs + (wn + i * 16 + l16) * 64;
        bf[i] = *(const s16x8*)(br + (((kk * 4 + quad) ^ swz) * 8));
      }
#pragma unroll
      for (int i = 0; i < 4; i++)
#pragma unroll
        for (int n = 0; n < 4; n++)
          acc[i][n] = __builtin_amdgcn_mfma_f32_16x16x32_bf16(af[i], bf[n], acc[i][n], 0, 0, 0);
    }
    __syncthreads();
  }

#pragma unroll
  for (int i = 0; i < 4; i++) {
    int row = m0 + wm + i * 16 + quad * 4;
#pragma unroll
    for (int n = 0; n < 4; n++) {
      int col = n0 + wn + n * 16 + l16;
#pragma unroll
      for (int r = 0; r < 4; r++)
        C[(size_t)(row + r) * N + col] = acc[i][n][r];
    }
  }
}

// ---------------- causal flash attention v9: v8 minus the spill ----------------
// Balanced pairing (tile p with tile 31-p). P pitch-64 with XOR slot swizzle
// (col ^ ((row&7)<<3), same involution write+read) -> 0 bank conflicts, LDS
// 40960 B. launch_bounds back to (256,3): the (256,4) bound clamped VGPR to
// 64 (< the ~84-reg live set) and caused a 348MB/dispatch scratch spill.
#define EXP2SCALE 0.18033688f   /* 0.125 * log2(e) */
#define EXP2OFF  17.312340f     /* 12 * log2(e) */
__global__ __launch_bounds__(256, 3) void attn(const ushort* __restrict__ Qb, const ushort* __restrict__ Kb,
                                               const ushort* __restrict__ Vt, ushort* __restrict__ Ob) {
  const int bh = blockIdx.x;
  const int p = blockIdx.y;        // pair index 0..15
  const int tid = threadIdx.x, wave = tid >> 6, lane = tid & 63;
  const int quad = lane >> 4, l16 = lane & 15;
  const int b = bh / H_, h = bh % H_;
  const ushort* Qp = Qb + (size_t)bh * T_ * DH;
  const ushort* Kp = Kb + (size_t)bh * T_ * DH;
  const ushort* Vp = Vt + (size_t)bh * DH * T_;

  __shared__ ushort Ks[2][64 * 64];
  __shared__ ushort Vs[2][64 * 64];
  __shared__ ushort P[4][16][64];   // per wave; XOR slot-swizzled

  const int myTile = (wave < 2) ? p : (31 - p);     // 64-row q tile
  const int qbase0 = myTile * 64 + (wave & 1) * 32; // this wave's 32 rows

  s16x8 aq[2][2];
#pragma unroll
  for (int m = 0; m < 2; m++) {
    const ushort* qp = Qp + (size_t)(qbase0 + m * 16 + l16) * DH + quad * 8;
    aq[m][0] = *(const s16x8*)qp;
    aq[m][1] = *(const s16x8*)(qp + 32);
  }
  f32x4 o[2][4] = {};
  float rsum[2][4] = {{0.f, 0.f, 0.f, 0.f}, {0.f, 0.f, 0.f, 0.f}};

  const int ntile = 32 - p;  // kv tiles 0..31-p cover tile 31-p; tile p subsets
  const int srow = tid >> 3;                   // 0..31
  const int scbK = (tid & 7) ^ (srow & 7);     // swizzled source colblock
  const int swz = (l16 & 7);

  {
    const int kv0 = 0;
    __builtin_amdgcn_global_load_lds((gas1_t)(Kp + (size_t)(kv0 + srow) * DH + scbK * 8),
                                     (las3_t)(Ks[0] + tid * 8), 16, 0, 0);
    __builtin_amdgcn_global_load_lds((gas1_t)(Kp + (size_t)(kv0 + srow + 32) * DH + scbK * 8),
                                     (las3_t)(Ks[0] + 2048 + tid * 8), 16, 0, 0);
    __builtin_amdgcn_global_load_lds((gas1_t)(Vp + (size_t)srow * T_ + kv0 + scbK * 8),
                                     (las3_t)(Vs[0] + tid * 8), 16, 0, 0);
    __builtin_amdgcn_global_load_lds((gas1_t)(Vp + (size_t)(srow + 32) * T_ + kv0 + scbK * 8),
                                     (las3_t)(Vs[0] + 2048 + tid * 8), 16, 0, 0);
  }

  for (int c = 0; c < ntile; c++) {
    const int kv0 = c * 64;
    const int cur = c & 1;
    __syncthreads();  // drains own vmcnt -> buf[cur] staged & visible
    if (c + 1 < ntile) {
      const int kv1 = kv0 + 64, nxt = cur ^ 1;
      __builtin_amdgcn_global_load_lds((gas1_t)(Kp + (size_t)(kv1 + srow) * DH + scbK * 8),
                                       (las3_t)(Ks[nxt] + tid * 8), 16, 0, 0);
      __builtin_amdgcn_global_load_lds((gas1_t)(Kp + (size_t)(kv1 + srow + 32) * DH + scbK * 8),
                                       (las3_t)(Ks[nxt] + 2048 + tid * 8), 16, 0, 0);
      __builtin_amdgcn_global_load_lds((gas1_t)(Vp + (size_t)srow * T_ + kv1 + scbK * 8),
                                       (las3_t)(Vs[nxt] + tid * 8), 16, 0, 0);
      __builtin_amdgcn_global_load_lds((gas1_t)(Vp + (size_t)(srow + 32) * T_ + kv1 + scbK * 8),
                                       (las3_t)(Vs[nxt] + 2048 + tid * 8), 16, 0, 0);
    }

    // wave-uniform: skip frag reads + compute entirely once past this wave's diagonal
    if (kv0 <= qbase0 + 31) {
      s16x8 kf[4][2];
#pragma unroll
      for (int nt = 0; nt < 4; nt++) {
        const ushort* kr = Ks[cur] + (nt * 16 + l16) * 64;
        kf[nt][0] = *(const s16x8*)(kr + ((quad ^ swz) * 8));
        kf[nt][1] = *(const s16x8*)(kr + (((4 + quad) ^ swz) * 8));
      }
      s16x8 bv[4][2];
#pragma unroll
      for (int dt = 0; dt < 4; dt++) {
        const ushort* vr = Vs[cur] + (dt * 16 + l16) * 64;
        bv[dt][0] = *(const s16x8*)(vr + ((quad ^ swz) * 8));
        bv[dt][1] = *(const s16x8*)(vr + (((4 + quad) ^ swz) * 8));
      }

#pragma unroll
      for (int m = 0; m < 2; m++) {
        const int qb = qbase0 + m * 16;
        if (kv0 > qb + 15) continue;  // fully masked frag (wave-uniform)
        f32x4 s[4] = {};
        __builtin_amdgcn_s_setprio(1);
#pragma unroll
        for (int nt = 0; nt < 4; nt++) {
          s[nt] = __builtin_amdgcn_mfma_f32_16x16x32_bf16(aq[m][0], kf[nt][0], s[nt], 0, 0, 0);
          s[nt] = __builtin_amdgcn_mfma_f32_16x16x32_bf16(aq[m][1], kf[nt][1], s[nt], 0, 0, 0);
        }
        __builtin_amdgcn_s_setprio(0);
        if (kv0 + 63 <= qb) {  // fully unmasked
#pragma unroll
          for (int nt = 0; nt < 4; nt++)
#pragma unroll
            for (int r = 0; r < 4; r++) {
              float pv = __builtin_amdgcn_exp2f(fmaf(s[nt][r], EXP2SCALE, -EXP2OFF));
              rsum[m][r] += pv;
              int row = quad * 4 + r;
              P[wave][row][(nt * 16 + l16) ^ ((row & 7) << 3)] = f2b(pv);
            }
        } else {  // diagonal tile
#pragma unroll
          for (int nt = 0; nt < 4; nt++) {
            int kv = kv0 + nt * 16 + l16;
#pragma unroll
            for (int r = 0; r < 4; r++) {
              int qi = qb + quad * 4 + r;
              float pv = (kv <= qi) ? __builtin_amdgcn_exp2f(fmaf(s[nt][r], EXP2SCALE, -EXP2OFF)) : 0.f;
              rsum[m][r] += pv;
              int row = quad * 4 + r;
              P[wave][row][(nt * 16 + l16) ^ ((row & 7) << 3)] = f2b(pv);
            }
          }
        }
        s16x8 ap0 = *(const s16x8*)&P[wave][l16][((0 + quad) ^ swz) * 8];
        s16x8 ap1 = *(const s16x8*)&P[wave][l16][((4 + quad) ^ swz) * 8];
        __builtin_amdgcn_s_setprio(1);
#pragma unroll
        for (int dt = 0; dt < 4; dt++) {
          o[m][dt] = __builtin_amdgcn_mfma_f32_16x16x32_bf16(ap0, bv[dt][0], o[m][dt], 0, 0, 0);
          o[m][dt] = __builtin_amdgcn_mfma_f32_16x16x32_bf16(ap1, bv[dt][1], o[m][dt], 0, 0, 0);
        }
        __builtin_amdgcn_s_setprio(0);
      }
    }
  }
#pragma unroll
  for (int off = 1; off < 16; off <<= 1)
#pragma unroll
    for (int m = 0; m < 2; m++)
#pragma unroll
      for (int r = 0; r < 4; r++)
        rsum[m][r] += __shfl_xor(rsum[m][r], off);
#pragma unroll
  for (int m = 0; m < 2; m++)
#pragma unroll
    for (int dt = 0; dt < 4; dt++)
#pragma unroll
      for (int r = 0; r < 4; r++) {
        int q = qbase0 + m * 16 + quad * 4 + r;
        Ob[(size_t)(b * T_ + q) * DM + h * 64 + dt * 16 + l16] = f2b(o[m][dt][r] / rsum[m][r]);
      }
}

extern "C" void kernel_launch(void* const* d_in, const int* in_sizes, int n_in,
                              void* d_out, int out_size, void* d_ws, size_t ws_size,
                              hipStream_t stream) {
  const float* x = (const float*)d_in[0];
  const float* rc = (const float*)d_in[1];
  const float* rs = (const float*)d_in[2];
  const float* wq = (const float*)d_in[3];
  const float* wk = (const float*)d_in[4];
  const float* wv = (const float*)d_in[5];
  const float* wo = (const float*)d_in[6];

  char* ws = (char*)d_ws;
  ushort* xb   = (ushort*)(ws);                 // 12,582,912
  ushort* wqkv = (ushort*)(ws + 12582912);      //  3,538,944
  ushort* wob  = (ushort*)(ws + 16121856);      //  1,179,648
  float2* cs2  = (float2*)(ws + 17301504);      //    524,288
  ushort* Qb   = (ushort*)(ws + 17825792);      // 12,582,912
  ushort* Kb   = (ushort*)(ws + 30408704);      // 12,582,912
  ushort* Vt   = (ushort*)(ws + 42991616);      // 12,582,912
  ushort* Ob   = (ushort*)(ws + 55574528);      // 12,582,912 (ends ~68.2MB)

  cvt_all<<<8704, 256, 0, stream>>>(x, wq, wk, wv, wo, rc, rs, xb, wqkv, wob, cs2);

  gemm_qkv<<<dim3(18, 64), 256, 0, stream>>>(xb, wqkv, cs2, Qb, Kb, Vt);

  attn<<<dim3(48, 16), 256, 0, stream>>>(Qb, Kb, Vt, Ob);

  gemm_out<<<dim3(6, 64), 256, 0, stream>>>(Ob, wob, (float*)d_out);
}

// Round 5
// 204.635 us; speedup vs baseline: 2.2072x; 1.1380x over previous
//
#include <hip/hip_runtime.h>
#include <hip/hip_bf16.h>
#include <math.h>

#define B_ 4
#define T_ 2048
#define DM 768
#define H_ 12
#define DH 64

typedef __attribute__((ext_vector_type(4))) float f32x4;
typedef __attribute__((ext_vector_type(8))) short s16x8;

typedef const __attribute__((address_space(1))) void* gas1_t;
typedef __attribute__((address_space(3))) void* las3_t;

__device__ __forceinline__ ushort f2b(float f) {
  union { float f; unsigned u; } v; v.f = f;
  unsigned u = v.u;
  u += 0x7fffu + ((u >> 16) & 1u);
  return (ushort)(u >> 16);
}
__device__ __forceinline__ float b2f(ushort b) {
  union { unsigned u; float f; } v; v.u = ((unsigned)b) << 16;
  return v.f;
}

// ---------------- fused fp32->bf16 conversions + rope pack, one launch ----------------
// blocks [0,6144): x -> xb ; [6144,8448): weights -> wqkv/wob ; [8448,8704): cos/sin pack
__global__ void cvt_all(const float* __restrict__ x,
                        const float* __restrict__ wq, const float* __restrict__ wk,
                        const float* __restrict__ wv, const float* __restrict__ wo,
                        const float* __restrict__ rc, const float* __restrict__ rs,
                        ushort* __restrict__ xb, ushort* __restrict__ wqkv,
                        ushort* __restrict__ wob, float2* __restrict__ cs2) {
  const int bid = blockIdx.x, t = threadIdx.x;
  if (bid < 6144) {
    int i = bid * 256 + t;
    float4 v = ((const float4*)x)[i];
    ushort4 o;
    o.x = f2b(v.x); o.y = f2b(v.y); o.z = f2b(v.z); o.w = f2b(v.w);
    ((ushort4*)xb)[i] = o;
  } else if (bid < 8448) {
    int i = (bid - 6144) * 256 + t;  // 0 .. 589823
    int which = i / 147456, j = i - which * 147456;
    const float* src = which == 0 ? wq : which == 1 ? wk : which == 2 ? wv : wo;
    ushort* dst = which < 3 ? wqkv + (size_t)which * 589824 : wob;
    float4 v = ((const float4*)src)[j];
    ushort4 o;
    o.x = f2b(v.x); o.y = f2b(v.y); o.z = f2b(v.z); o.w = f2b(v.w);
    ((ushort4*)dst)[j] = o;
  } else {
    int i = (bid - 8448) * 256 + t;  // 0 .. 65535
    cs2[i] = make_float2(rc[i], rs[i]);
  }
}

// ---------------- QKV GEMM, BK=64, XCD-partitioned block decode ----------------
// 1-D grid of 1152 = 8 XCD x 8 m-panels x 18 n-panels. XCD = bid%8 (HW round
// robin), so each XCD owns 8 A-panels (1.6 MB, L2-resident across its 18
// n-blocks) instead of re-fetching all 64.
__global__ __launch_bounds__(256, 3) void gemm_qkv(
    const ushort* __restrict__ A, const ushort* __restrict__ Bw,
    const float2* __restrict__ cs2,
    ushort* __restrict__ Qb, ushort* __restrict__ Kb, ushort* __restrict__ Vt) {
  const int K = 768;
  __shared__ ushort As[128 * 64];
  __shared__ ushort Bs[128 * 64];
  const int bid = blockIdx.x;
  const int xcd = bid & 7;
  const int jj = bid >> 3;               // 0..143
  const int mloc = jj / 18, nn0 = jj - mloc * 18;
  const int m0 = (xcd * 8 + mloc) * 128, n0 = nn0 * 128;
  const int tid = threadIdx.x;
  const int wave = tid >> 6, lane = tid & 63;
  const int wm = (wave >> 1) * 64, wn = (wave & 1) * 64;
  const int quad = lane >> 4, l16 = lane & 15;
  const int tr = tid >> 3;                 // staging row 0..31 (per 32-row pass)
  const int scb = (tid & 7) ^ (tr & 7);    // pre-swizzled source colblock
  const int swz = l16 & 7;                 // frag-read swizzle term (= row&7)

  f32x4 acc[4][4] = {};

  const ushort* ga = A + (size_t)(m0 + tr) * K + scb * 8;
  const ushort* gb = Bw + (size_t)(n0 + tr) * K + scb * 8;

  for (int k0 = 0; k0 < K; k0 += 64) {
#pragma unroll
    for (int p = 0; p < 4; p++) {
      __builtin_amdgcn_global_load_lds((gas1_t)(ga + (size_t)(p * 32) * K + k0),
                                       (las3_t)(As + p * 2048 + tid * 8), 16, 0, 0);
      __builtin_amdgcn_global_load_lds((gas1_t)(gb + (size_t)(p * 32) * K + k0),
                                       (las3_t)(Bs + p * 2048 + tid * 8), 16, 0, 0);
    }
    __syncthreads();
#pragma unroll
    for (int kk = 0; kk < 2; kk++) {
      s16x8 af[4], bf[4];
#pragma unroll
      for (int i = 0; i < 4; i++) {
        const ushort* ar = As + (wm + i * 16 + l16) * 64;
        af[i] = *(const s16x8*)(ar + (((kk * 4 + quad) ^ swz) * 8));
        const ushort* br = Bs + (wn + i * 16 + l16) * 64;
        bf[i] = *(const s16x8*)(br + (((kk * 4 + quad) ^ swz) * 8));
      }
#pragma unroll
      for (int i = 0; i < 4; i++)
#pragma unroll
        for (int n = 0; n < 4; n++)
          acc[i][n] = __builtin_amdgcn_mfma_f32_16x16x32_bf16(af[i], bf[n], acc[i][n], 0, 0, 0);
    }
    __syncthreads();
  }

  const int sec = n0 / 768;  // 0=q, 1=k, 2=v (uniform per block)
  if (sec < 2) {
    ushort* dst = sec == 0 ? Qb : Kb;
#pragma unroll
    for (int i = 0; i < 4; i++) {
      int row0 = m0 + wm + i * 16 + quad * 4;
#pragma unroll
      for (int nt = 0; nt < 4; nt++) {
        int col = n0 + wn + nt * 16 + l16;
        int nv = col - sec * 768;
        int h = nv >> 6, d = nv & 63;
        int ip = (d >> 1) & 31;
        float sgn = (d & 1) ? 1.f : -1.f;
#pragma unroll
        for (int r = 0; r < 4; r++) {
          int rrow = row0 + r;
          int t = rrow & (T_ - 1), bb = rrow >> 11;
          float v = acc[i][nt][r];
          float partner = __shfl_xor(v, 1);
          float2 cs = cs2[t * 32 + ip];
          float out = fmaf(v, cs.x, sgn * partner * cs.y);
          dst[((size_t)(bb * H_ + h) * T_ + t) * DH + d] = f2b(out);
        }
      }
    }
  } else {
#pragma unroll
    for (int i = 0; i < 4; i++) {
      int row0 = m0 + wm + i * 16 + quad * 4;
      int t0 = row0 & (T_ - 1), b = row0 >> 11;  // 4 rows share b (aligned)
#pragma unroll
      for (int nt = 0; nt < 4; nt++) {
        int col = n0 + wn + nt * 16 + l16;
        int nv = col - 1536;
        int h = nv >> 6, d = nv & 63;
        ushort4 pk;
        pk.x = f2b(acc[i][nt][0]); pk.y = f2b(acc[i][nt][1]);
        pk.z = f2b(acc[i][nt][2]); pk.w = f2b(acc[i][nt][3]);
        *(ushort4*)(Vt + ((size_t)(b * H_ + h) * DH + d) * T_ + t0) = pk;
      }
    }
  }
}

// ---------------- output GEMM: 128x128 tiles, BK=64, XCD-partitioned ----------------
// 384 = 8 XCD x 8 m x 6 n.
__global__ __launch_bounds__(256, 3) void gemm_out(
    const ushort* __restrict__ A, const ushort* __restrict__ Bw, float* __restrict__ C) {
  const int K = 768, N = 768;
  __shared__ ushort As[128 * 64];
  __shared__ ushort Bs[128 * 64];
  const int bid = blockIdx.x;
  const int xcd = bid & 7;
  const int jj = bid >> 3;               // 0..47
  const int mloc = jj / 6, nn0 = jj - mloc * 6;
  const int m0 = (xcd * 8 + mloc) * 128, n0 = nn0 * 128;
  const int tid = threadIdx.x;
  const int wave = tid >> 6, lane = tid & 63;
  const int wm = (wave >> 1) * 64, wn = (wave & 1) * 64;
  const int quad = lane >> 4, l16 = lane & 15;
  const int tr = tid >> 3;
  const int scb = (tid & 7) ^ (tr & 7);
  const int swz = l16 & 7;

  f32x4 acc[4][4] = {};

  const ushort* ga = A + (size_t)(m0 + tr) * K + scb * 8;
  const ushort* gb = Bw + (size_t)(n0 + tr) * K + scb * 8;

  for (int k0 = 0; k0 < K; k0 += 64) {
#pragma unroll
    for (int p = 0; p < 4; p++) {
      __builtin_amdgcn_global_load_lds((gas1_t)(ga + (size_t)(p * 32) * K + k0),
                                       (las3_t)(As + p * 2048 + tid * 8), 16, 0, 0);
      __builtin_amdgcn_global_load_lds((gas1_t)(gb + (size_t)(p * 32) * K + k0),
                                       (las3_t)(Bs + p * 2048 + tid * 8), 16, 0, 0);
    }
    __syncthreads();
#pragma unroll
    for (int kk = 0; kk < 2; kk++) {
      s16x8 af[4], bf[4];
#pragma unroll
      for (int i = 0; i < 4; i++) {
        const ushort* ar = As + (wm + i * 16 + l16) * 64;
        af[i] = *(const s16x8*)(ar + (((kk * 4 + quad) ^ swz) * 8));
        const ushort* br = Bs + (wn + i * 16 + l16) * 64;
        bf[i] = *(const s16x8*)(br + (((kk * 4 + quad) ^ swz) * 8));
      }
#pragma unroll
      for (int i = 0; i < 4; i++)
#pragma unroll
        for (int n = 0; n < 4; n++)
          acc[i][n] = __builtin_amdgcn_mfma_f32_16x16x32_bf16(af[i], bf[n], acc[i][n], 0, 0, 0);
    }
    __syncthreads();
  }

#pragma unroll
  for (int i = 0; i < 4; i++) {
    int row = m0 + wm + i * 16 + quad * 4;
#pragma unroll
    for (int n = 0; n < 4; n++) {
      int col = n0 + wn + n * 16 + l16;
#pragma unroll
      for (int r = 0; r < 4; r++)
        C[(size_t)(row + r) * N + col] = acc[i][n][r];
    }
  }
}

// ---------------- causal flash attention v10 == round-1 v7 (proven 67 us) ----------------
// Balanced pairing (tile p with tile 31-p). P pitch-72, plain reads, NO
// setprio (setprio regressed this barrier-synced 4-wave structure: 67->80us).
#define EXP2SCALE 0.18033688f   /* 0.125 * log2(e) */
#define EXP2OFF  17.312340f     /* 12 * log2(e) */
__global__ __launch_bounds__(256, 3) void attn(const ushort* __restrict__ Qb, const ushort* __restrict__ Kb,
                                               const ushort* __restrict__ Vt, ushort* __restrict__ Ob) {
  const int bh = blockIdx.x;
  const int p = blockIdx.y;        // pair index 0..15
  const int tid = threadIdx.x, wave = tid >> 6, lane = tid & 63;
  const int quad = lane >> 4, l16 = lane & 15;
  const int b = bh / H_, h = bh % H_;
  const ushort* Qp = Qb + (size_t)bh * T_ * DH;
  const ushort* Kp = Kb + (size_t)bh * T_ * DH;
  const ushort* Vp = Vt + (size_t)bh * DH * T_;

  __shared__ ushort Ks[2][64 * 64];
  __shared__ ushort Vs[2][64 * 64];
  __shared__ ushort P[4][16][72];   // per wave, shared across m-frags

  const int myTile = (wave < 2) ? p : (31 - p);     // 64-row q tile
  const int qbase0 = myTile * 64 + (wave & 1) * 32; // this wave's 32 rows

  s16x8 aq[2][2];
#pragma unroll
  for (int m = 0; m < 2; m++) {
    const ushort* qp = Qp + (size_t)(qbase0 + m * 16 + l16) * DH + quad * 8;
    aq[m][0] = *(const s16x8*)qp;
    aq[m][1] = *(const s16x8*)(qp + 32);
  }
  f32x4 o[2][4] = {};
  float rsum[2][4] = {{0.f, 0.f, 0.f, 0.f}, {0.f, 0.f, 0.f, 0.f}};

  const int ntile = 32 - p;  // kv tiles 0..31-p cover tile 31-p; tile p subsets
  const int srow = tid >> 3;                   // 0..31
  const int scbK = (tid & 7) ^ (srow & 7);     // swizzled source colblock
  const int swz = (l16 & 7);

  {
    const int kv0 = 0;
    __builtin_amdgcn_global_load_lds((gas1_t)(Kp + (size_t)(kv0 + srow) * DH + scbK * 8),
                                     (las3_t)(Ks[0] + tid * 8), 16, 0, 0);
    __builtin_amdgcn_global_load_lds((gas1_t)(Kp + (size_t)(kv0 + srow + 32) * DH + scbK * 8),
                                     (las3_t)(Ks[0] + 2048 + tid * 8), 16, 0, 0);
    __builtin_amdgcn_global_load_lds((gas1_t)(Vp + (size_t)srow * T_ + kv0 + scbK * 8),
                                     (las3_t)(Vs[0] + tid * 8), 16, 0, 0);
    __builtin_amdgcn_global_load_lds((gas1_t)(Vp + (size_t)(srow + 32) * T_ + kv0 + scbK * 8),
                                     (las3_t)(Vs[0] + 2048 + tid * 8), 16, 0, 0);
  }

  for (int c = 0; c < ntile; c++) {
    const int kv0 = c * 64;
    const int cur = c & 1;
    __syncthreads();  // drains own vmcnt -> buf[cur] staged & visible
    if (c + 1 < ntile) {
      const int kv1 = kv0 + 64, nxt = cur ^ 1;
      __builtin_amdgcn_global_load_lds((gas1_t)(Kp + (size_t)(kv1 + srow) * DH + scbK * 8),
                                       (las3_t)(Ks[nxt] + tid * 8), 16, 0, 0);
      __builtin_amdgcn_global_load_lds((gas1_t)(Kp + (size_t)(kv1 + srow + 32) * DH + scbK * 8),
                                       (las3_t)(Ks[nxt] + 2048 + tid * 8), 16, 0, 0);
      __builtin_amdgcn_global_load_lds((gas1_t)(Vp + (size_t)srow * T_ + kv1 + scbK * 8),
                                       (las3_t)(Vs[nxt] + tid * 8), 16, 0, 0);
      __builtin_amdgcn_global_load_lds((gas1_t)(Vp + (size_t)(srow + 32) * T_ + kv1 + scbK * 8),
                                       (las3_t)(Vs[nxt] + 2048 + tid * 8), 16, 0, 0);
    }

    // wave-uniform: skip frag reads + compute entirely once past this wave's diagonal
    if (kv0 <= qbase0 + 31) {
      s16x8 kf[4][2];
#pragma unroll
      for (int nt = 0; nt < 4; nt++) {
        const ushort* kr = Ks[cur] + (nt * 16 + l16) * 64;
        kf[nt][0] = *(const s16x8*)(kr + ((quad ^ swz) * 8));
        kf[nt][1] = *(const s16x8*)(kr + (((4 + quad) ^ swz) * 8));
      }
      s16x8 bv[4][2];
#pragma unroll
      for (int dt = 0; dt < 4; dt++) {
        const ushort* vr = Vs[cur] + (dt * 16 + l16) * 64;
        bv[dt][0] = *(const s16x8*)(vr + ((quad ^ swz) * 8));
        bv[dt][1] = *(const s16x8*)(vr + (((4 + quad) ^ swz) * 8));
      }

#pragma unroll
      for (int m = 0; m < 2; m++) {
        const int qb = qbase0 + m * 16;
        if (kv0 > qb + 15) continue;  // fully masked frag (wave-uniform)
        f32x4 s[4] = {};
#pragma unroll
        for (int nt = 0; nt < 4; nt++) {
          s[nt] = __builtin_amdgcn_mfma_f32_16x16x32_bf16(aq[m][0], kf[nt][0], s[nt], 0, 0, 0);
          s[nt] = __builtin_amdgcn_mfma_f32_16x16x32_bf16(aq[m][1], kf[nt][1], s[nt], 0, 0, 0);
        }
        if (kv0 + 63 <= qb) {  // fully unmasked
#pragma unroll
          for (int nt = 0; nt < 4; nt++)
#pragma unroll
            for (int r = 0; r < 4; r++) {
              float pv = __builtin_amdgcn_exp2f(fmaf(s[nt][r], EXP2SCALE, -EXP2OFF));
              rsum[m][r] += pv;
              P[wave][quad * 4 + r][nt * 16 + l16] = f2b(pv);
            }
        } else {  // diagonal tile
#pragma unroll
          for (int nt = 0; nt < 4; nt++) {
            int kv = kv0 + nt * 16 + l16;
#pragma unroll
            for (int r = 0; r < 4; r++) {
              int qi = qb + quad * 4 + r;
              float pv = (kv <= qi) ? __builtin_amdgcn_exp2f(fmaf(s[nt][r], EXP2SCALE, -EXP2OFF)) : 0.f;
              rsum[m][r] += pv;
              P[wave][quad * 4 + r][nt * 16 + l16] = f2b(pv);
            }
          }
        }
        s16x8 ap0 = *(const s16x8*)&P[wave][l16][quad * 8];
        s16x8 ap1 = *(const s16x8*)&P[wave][l16][32 + quad * 8];
#pragma unroll
        for (int dt = 0; dt < 4; dt++) {
          o[m][dt] = __builtin_amdgcn_mfma_f32_16x16x32_bf16(ap0, bv[dt][0], o[m][dt], 0, 0, 0);
          o[m][dt] = __builtin_amdgcn_mfma_f32_16x16x32_bf16(ap1, bv[dt][1], o[m][dt], 0, 0, 0);
        }
      }
    }
  }
#pragma unroll
  for (int off = 1; off < 16; off <<= 1)
#pragma unroll
    for (int m = 0; m < 2; m++)
#pragma unroll
      for (int r = 0; r < 4; r++)
        rsum[m][r] += __shfl_xor(rsum[m][r], off);
#pragma unroll
  for (int m = 0; m < 2; m++)
#pragma unroll
    for (int dt = 0; dt < 4; dt++)
#pragma unroll
      for (int r = 0; r < 4; r++) {
        int q = qbase0 + m * 16 + quad * 4 + r;
        Ob[(size_t)(b * T_ + q) * DM + h * 64 + dt * 16 + l16] = f2b(o[m][dt][r] / rsum[m][r]);
      }
}

extern "C" void kernel_launch(void* const* d_in, const int* in_sizes, int n_in,
                              void* d_out, int out_size, void* d_ws, size_t ws_size,
                              hipStream_t stream) {
  const float* x = (const float*)d_in[0];
  const float* rc = (const float*)d_in[1];
  const float* rs = (const float*)d_in[2];
  const float* wq = (const float*)d_in[3];
  const float* wk = (const float*)d_in[4];
  const float* wv = (const float*)d_in[5];
  const float* wo = (const float*)d_in[6];

  char* ws = (char*)d_ws;
  ushort* xb   = (ushort*)(ws);                 // 12,582,912
  ushort* wqkv = (ushort*)(ws + 12582912);      //  3,538,944
  ushort* wob  = (ushort*)(ws + 16121856);      //  1,179,648
  float2* cs2  = (float2*)(ws + 17301504);      //    524,288
  ushort* Qb   = (ushort*)(ws + 17825792);      // 12,582,912
  ushort* Kb   = (ushort*)(ws + 30408704);      // 12,582,912
  ushort* Vt   = (ushort*)(ws + 42991616);      // 12,582,912
  ushort* Ob   = (ushort*)(ws + 55574528);      // 12,582,912 (ends ~68.2MB)

  cvt_all<<<8704, 256, 0, stream>>>(x, wq, wk, wv, wo, rc, rs, xb, wqkv, wob, cs2);

  gemm_qkv<<<1152, 256, 0, stream>>>(xb, wqkv, cs2, Qb, Kb, Vt);

  attn<<<dim3(48, 16), 256, 0, stream>>>(Qb, Kb, Vt, Ob);

  gemm_out<<<384, 256, 0, stream>>>(Ob, wob, (float*)d_out);
}

// Round 6
// 195.506 us; speedup vs baseline: 2.3103x; 1.0467x over previous
//
#include <hip/hip_runtime.h>
#include <hip/hip_bf16.h>
#include <math.h>

#define B_ 4
#define T_ 2048
#define DM 768
#define H_ 12
#define DH 64

typedef __attribute__((ext_vector_type(4))) float f32x4;
typedef __attribute__((ext_vector_type(8))) short s16x8;

typedef const __attribute__((address_space(1))) void* gas1_t;
typedef __attribute__((address_space(3))) void* las3_t;

__device__ __forceinline__ ushort f2b(float f) {
  union { float f; unsigned u; } v; v.f = f;
  unsigned u = v.u;
  u += 0x7fffu + ((u >> 16) & 1u);
  return (ushort)(u >> 16);
}
__device__ __forceinline__ float b2f(ushort b) {
  union { unsigned u; float f; } v; v.u = ((unsigned)b) << 16;
  return v.f;
}
// packed f32x2 -> bf16x2 (RNE, same rounding as f2b) in one instruction
__device__ __forceinline__ unsigned cvt_pk_bf16(float lo, float hi) {
  unsigned r;
  asm("v_cvt_pk_bf16_f32 %0, %1, %2" : "=v"(r) : "v"(lo), "v"(hi));
  return r;
}

// ---------------- fused fp32->bf16 conversions + rope pack, one launch ----------------
// blocks [0,6144): x -> xb ; [6144,8448): weights -> wqkv/wob ; [8448,8704): cos/sin pack
__global__ void cvt_all(const float* __restrict__ x,
                        const float* __restrict__ wq, const float* __restrict__ wk,
                        const float* __restrict__ wv, const float* __restrict__ wo,
                        const float* __restrict__ rc, const float* __restrict__ rs,
                        ushort* __restrict__ xb, ushort* __restrict__ wqkv,
                        ushort* __restrict__ wob, float2* __restrict__ cs2) {
  const int bid = blockIdx.x, t = threadIdx.x;
  if (bid < 6144) {
    int i = bid * 256 + t;
    float4 v = ((const float4*)x)[i];
    ushort4 o;
    o.x = f2b(v.x); o.y = f2b(v.y); o.z = f2b(v.z); o.w = f2b(v.w);
    ((ushort4*)xb)[i] = o;
  } else if (bid < 8448) {
    int i = (bid - 6144) * 256 + t;  // 0 .. 589823
    int which = i / 147456, j = i - which * 147456;
    const float* src = which == 0 ? wq : which == 1 ? wk : which == 2 ? wv : wo;
    ushort* dst = which < 3 ? wqkv + (size_t)which * 589824 : wob;
    float4 v = ((const float4*)src)[j];
    ushort4 o;
    o.x = f2b(v.x); o.y = f2b(v.y); o.z = f2b(v.z); o.w = f2b(v.w);
    ((ushort4*)dst)[j] = o;
  } else {
    int i = (bid - 8448) * 256 + t;  // 0 .. 65535
    cs2[i] = make_float2(rc[i], rs[i]);
  }
}

// ---------------- QKV GEMM, BK=64, XCD-partitioned block decode ----------------
// 1-D grid of 1152 = 8 XCD x 8 m-panels x 18 n-panels. XCD = bid%8 (HW round
// robin), so each XCD owns 8 A-panels (1.6 MB, L2-resident across its 18
// n-blocks) instead of re-fetching all 64.
__global__ __launch_bounds__(256, 3) void gemm_qkv(
    const ushort* __restrict__ A, const ushort* __restrict__ Bw,
    const float2* __restrict__ cs2,
    ushort* __restrict__ Qb, ushort* __restrict__ Kb, ushort* __restrict__ Vt) {
  const int K = 768;
  __shared__ ushort As[128 * 64];
  __shared__ ushort Bs[128 * 64];
  const int bid = blockIdx.x;
  const int xcd = bid & 7;
  const int jj = bid >> 3;               // 0..143
  const int mloc = jj / 18, nn0 = jj - mloc * 18;
  const int m0 = (xcd * 8 + mloc) * 128, n0 = nn0 * 128;
  const int tid = threadIdx.x;
  const int wave = tid >> 6, lane = tid & 63;
  const int wm = (wave >> 1) * 64, wn = (wave & 1) * 64;
  const int quad = lane >> 4, l16 = lane & 15;
  const int tr = tid >> 3;                 // staging row 0..31 (per 32-row pass)
  const int scb = (tid & 7) ^ (tr & 7);    // pre-swizzled source colblock
  const int swz = l16 & 7;                 // frag-read swizzle term (= row&7)

  f32x4 acc[4][4] = {};

  const ushort* ga = A + (size_t)(m0 + tr) * K + scb * 8;
  const ushort* gb = Bw + (size_t)(n0 + tr) * K + scb * 8;

  for (int k0 = 0; k0 < K; k0 += 64) {
#pragma unroll
    for (int p = 0; p < 4; p++) {
      __builtin_amdgcn_global_load_lds((gas1_t)(ga + (size_t)(p * 32) * K + k0),
                                       (las3_t)(As + p * 2048 + tid * 8), 16, 0, 0);
      __builtin_amdgcn_global_load_lds((gas1_t)(gb + (size_t)(p * 32) * K + k0),
                                       (las3_t)(Bs + p * 2048 + tid * 8), 16, 0, 0);
    }
    __syncthreads();
#pragma unroll
    for (int kk = 0; kk < 2; kk++) {
      s16x8 af[4], bf[4];
#pragma unroll
      for (int i = 0; i < 4; i++) {
        const ushort* ar = As + (wm + i * 16 + l16) * 64;
        af[i] = *(const s16x8*)(ar + (((kk * 4 + quad) ^ swz) * 8));
        const ushort* br = Bs + (wn + i * 16 + l16) * 64;
        bf[i] = *(const s16x8*)(br + (((kk * 4 + quad) ^ swz) * 8));
      }
#pragma unroll
      for (int i = 0; i < 4; i++)
#pragma unroll
        for (int n = 0; n < 4; n++)
          acc[i][n] = __builtin_amdgcn_mfma_f32_16x16x32_bf16(af[i], bf[n], acc[i][n], 0, 0, 0);
    }
    __syncthreads();
  }

  const int sec = n0 / 768;  // 0=q, 1=k, 2=v (uniform per block)
  if (sec < 2) {
    ushort* dst = sec == 0 ? Qb : Kb;
#pragma unroll
    for (int i = 0; i < 4; i++) {
      int row0 = m0 + wm + i * 16 + quad * 4;
#pragma unroll
      for (int nt = 0; nt < 4; nt++) {
        int col = n0 + wn + nt * 16 + l16;
        int nv = col - sec * 768;
        int h = nv >> 6, d = nv & 63;
        int ip = (d >> 1) & 31;
        float sgn = (d & 1) ? 1.f : -1.f;
#pragma unroll
        for (int r = 0; r < 4; r++) {
          int rrow = row0 + r;
          int t = rrow & (T_ - 1), bb = rrow >> 11;
          float v = acc[i][nt][r];
          float partner = __shfl_xor(v, 1);
          float2 cs = cs2[t * 32 + ip];
          float out = fmaf(v, cs.x, sgn * partner * cs.y);
          dst[((size_t)(bb * H_ + h) * T_ + t) * DH + d] = f2b(out);
        }
      }
    }
  } else {
#pragma unroll
    for (int i = 0; i < 4; i++) {
      int row0 = m0 + wm + i * 16 + quad * 4;
      int t0 = row0 & (T_ - 1), b = row0 >> 11;  // 4 rows share b (aligned)
#pragma unroll
      for (int nt = 0; nt < 4; nt++) {
        int col = n0 + wn + nt * 16 + l16;
        int nv = col - 1536;
        int h = nv >> 6, d = nv & 63;
        ushort4 pk;
        pk.x = f2b(acc[i][nt][0]); pk.y = f2b(acc[i][nt][1]);
        pk.z = f2b(acc[i][nt][2]); pk.w = f2b(acc[i][nt][3]);
        *(ushort4*)(Vt + ((size_t)(b * H_ + h) * DH + d) * T_ + t0) = pk;
      }
    }
  }
}

// ---------------- output GEMM: 128x128 tiles, BK=64, XCD-partitioned ----------------
// 384 = 8 XCD x 8 m x 6 n.
__global__ __launch_bounds__(256, 3) void gemm_out(
    const ushort* __restrict__ A, const ushort* __restrict__ Bw, float* __restrict__ C) {
  const int K = 768, N = 768;
  __shared__ ushort As[128 * 64];
  __shared__ ushort Bs[128 * 64];
  const int bid = blockIdx.x;
  const int xcd = bid & 7;
  const int jj = bid >> 3;               // 0..47
  const int mloc = jj / 6, nn0 = jj - mloc * 6;
  const int m0 = (xcd * 8 + mloc) * 128, n0 = nn0 * 128;
  const int tid = threadIdx.x;
  const int wave = tid >> 6, lane = tid & 63;
  const int wm = (wave >> 1) * 64, wn = (wave & 1) * 64;
  const int quad = lane >> 4, l16 = lane & 15;
  const int tr = tid >> 3;
  const int scb = (tid & 7) ^ (tr & 7);
  const int swz = l16 & 7;

  f32x4 acc[4][4] = {};

  const ushort* ga = A + (size_t)(m0 + tr) * K + scb * 8;
  const ushort* gb = Bw + (size_t)(n0 + tr) * K + scb * 8;

  for (int k0 = 0; k0 < K; k0 += 64) {
#pragma unroll
    for (int p = 0; p < 4; p++) {
      __builtin_amdgcn_global_load_lds((gas1_t)(ga + (size_t)(p * 32) * K + k0),
                                       (las3_t)(As + p * 2048 + tid * 8), 16, 0, 0);
      __builtin_amdgcn_global_load_lds((gas1_t)(gb + (size_t)(p * 32) * K + k0),
                                       (las3_t)(Bs + p * 2048 + tid * 8), 16, 0, 0);
    }
    __syncthreads();
#pragma unroll
    for (int kk = 0; kk < 2; kk++) {
      s16x8 af[4], bf[4];
#pragma unroll
      for (int i = 0; i < 4; i++) {
        const ushort* ar = As + (wm + i * 16 + l16) * 64;
        af[i] = *(const s16x8*)(ar + (((kk * 4 + quad) ^ swz) * 8));
        const ushort* br = Bs + (wn + i * 16 + l16) * 64;
        bf[i] = *(const s16x8*)(br + (((kk * 4 + quad) ^ swz) * 8));
      }
#pragma unroll
      for (int i = 0; i < 4; i++)
#pragma unroll
        for (int n = 0; n < 4; n++)
          acc[i][n] = __builtin_amdgcn_mfma_f32_16x16x32_bf16(af[i], bf[n], acc[i][n], 0, 0, 0);
    }
    __syncthreads();
  }

#pragma unroll
  for (int i = 0; i < 4; i++) {
    int row = m0 + wm + i * 16 + quad * 4;
#pragma unroll
    for (int n = 0; n < 4; n++) {
      int col = n0 + wn + n * 16 + l16;
#pragma unroll
      for (int r = 0; r < 4; r++)
        C[(size_t)(row + r) * N + col] = acc[i][n][r];
    }
  }
}

// ---------------- causal flash attention v11: swapped QK^T + packed P ----------------
// S^T = mfma(K, Q): lane holds 4 consecutive kv for ONE q (=l16), so the
// P write packs via v_cvt_pk_bf16_f32 (2 ops) + one ds_write_b64 per nt,
// replacing ~16 f2b bit-twiddle ops + 4 scalar b16 writes. PV reads and o
// layout unchanged. rsum: one scalar/lane (its q=l16), reduced with 2
// shfl_xor (16,32). No setprio (regressed this structure).
#define EXP2SCALE 0.18033688f   /* 0.125 * log2(e) */
#define EXP2OFF  17.312340f     /* 12 * log2(e) */
__global__ __launch_bounds__(256, 3) void attn(const ushort* __restrict__ Qb, const ushort* __restrict__ Kb,
                                               const ushort* __restrict__ Vt, ushort* __restrict__ Ob) {
  const int bh = blockIdx.x;
  const int p = blockIdx.y;        // pair index 0..15
  const int tid = threadIdx.x, wave = tid >> 6, lane = tid & 63;
  const int quad = lane >> 4, l16 = lane & 15;
  const int b = bh / H_, h = bh % H_;
  const ushort* Qp = Qb + (size_t)bh * T_ * DH;
  const ushort* Kp = Kb + (size_t)bh * T_ * DH;
  const ushort* Vp = Vt + (size_t)bh * DH * T_;

  __shared__ ushort Ks[2][64 * 64];
  __shared__ ushort Vs[2][64 * 64];
  __shared__ ushort P[4][16][72];   // per wave; row = q (l16), col = kv

  const int myTile = (wave < 2) ? p : (31 - p);     // 64-row q tile
  const int qbase0 = myTile * 64 + (wave & 1) * 32; // this wave's 32 rows

  s16x8 aq[2][2];
#pragma unroll
  for (int m = 0; m < 2; m++) {
    const ushort* qp = Qp + (size_t)(qbase0 + m * 16 + l16) * DH + quad * 8;
    aq[m][0] = *(const s16x8*)qp;
    aq[m][1] = *(const s16x8*)(qp + 32);
  }
  f32x4 o[2][4] = {};
  float rsum[2] = {0.f, 0.f};

  const int ntile = 32 - p;  // kv tiles 0..31-p cover tile 31-p; tile p subsets
  const int srow = tid >> 3;                   // 0..31
  const int scbK = (tid & 7) ^ (srow & 7);     // swizzled source colblock
  const int swz = (l16 & 7);

  {
    const int kv0 = 0;
    __builtin_amdgcn_global_load_lds((gas1_t)(Kp + (size_t)(kv0 + srow) * DH + scbK * 8),
                                     (las3_t)(Ks[0] + tid * 8), 16, 0, 0);
    __builtin_amdgcn_global_load_lds((gas1_t)(Kp + (size_t)(kv0 + srow + 32) * DH + scbK * 8),
                                     (las3_t)(Ks[0] + 2048 + tid * 8), 16, 0, 0);
    __builtin_amdgcn_global_load_lds((gas1_t)(Vp + (size_t)srow * T_ + kv0 + scbK * 8),
                                     (las3_t)(Vs[0] + tid * 8), 16, 0, 0);
    __builtin_amdgcn_global_load_lds((gas1_t)(Vp + (size_t)(srow + 32) * T_ + kv0 + scbK * 8),
                                     (las3_t)(Vs[0] + 2048 + tid * 8), 16, 0, 0);
  }

  for (int c = 0; c < ntile; c++) {
    const int kv0 = c * 64;
    const int cur = c & 1;
    __syncthreads();  // drains own vmcnt -> buf[cur] staged & visible
    if (c + 1 < ntile) {
      const int kv1 = kv0 + 64, nxt = cur ^ 1;
      __builtin_amdgcn_global_load_lds((gas1_t)(Kp + (size_t)(kv1 + srow) * DH + scbK * 8),
                                       (las3_t)(Ks[nxt] + tid * 8), 16, 0, 0);
      __builtin_amdgcn_global_load_lds((gas1_t)(Kp + (size_t)(kv1 + srow + 32) * DH + scbK * 8),
                                       (las3_t)(Ks[nxt] + 2048 + tid * 8), 16, 0, 0);
      __builtin_amdgcn_global_load_lds((gas1_t)(Vp + (size_t)srow * T_ + kv1 + scbK * 8),
                                       (las3_t)(Vs[nxt] + tid * 8), 16, 0, 0);
      __builtin_amdgcn_global_load_lds((gas1_t)(Vp + (size_t)(srow + 32) * T_ + kv1 + scbK * 8),
                                       (las3_t)(Vs[nxt] + 2048 + tid * 8), 16, 0, 0);
    }

    // wave-uniform: skip frag reads + compute entirely once past this wave's diagonal
    if (kv0 <= qbase0 + 31) {
      s16x8 kf[4][2];
#pragma unroll
      for (int nt = 0; nt < 4; nt++) {
        const ushort* kr = Ks[cur] + (nt * 16 + l16) * 64;
        kf[nt][0] = *(const s16x8*)(kr + ((quad ^ swz) * 8));
        kf[nt][1] = *(const s16x8*)(kr + (((4 + quad) ^ swz) * 8));
      }
      s16x8 bv[4][2];
#pragma unroll
      for (int dt = 0; dt < 4; dt++) {
        const ushort* vr = Vs[cur] + (dt * 16 + l16) * 64;
        bv[dt][0] = *(const s16x8*)(vr + ((quad ^ swz) * 8));
        bv[dt][1] = *(const s16x8*)(vr + (((4 + quad) ^ swz) * 8));
      }

#pragma unroll
      for (int m = 0; m < 2; m++) {
        const int qb = qbase0 + m * 16;
        if (kv0 > qb + 15) continue;  // fully masked frag (wave-uniform)
        // S^T: rows = kv (quad*4+r within nt), cols = q (l16)
        f32x4 s[4] = {};
#pragma unroll
        for (int nt = 0; nt < 4; nt++) {
          s[nt] = __builtin_amdgcn_mfma_f32_16x16x32_bf16(kf[nt][0], aq[m][0], s[nt], 0, 0, 0);
          s[nt] = __builtin_amdgcn_mfma_f32_16x16x32_bf16(kf[nt][1], aq[m][1], s[nt], 0, 0, 0);
        }
        if (kv0 + 63 <= qb) {  // fully unmasked
#pragma unroll
          for (int nt = 0; nt < 4; nt++) {
            float p0 = __builtin_amdgcn_exp2f(fmaf(s[nt][0], EXP2SCALE, -EXP2OFF));
            float p1 = __builtin_amdgcn_exp2f(fmaf(s[nt][1], EXP2SCALE, -EXP2OFF));
            float p2 = __builtin_amdgcn_exp2f(fmaf(s[nt][2], EXP2SCALE, -EXP2OFF));
            float p3 = __builtin_amdgcn_exp2f(fmaf(s[nt][3], EXP2SCALE, -EXP2OFF));
            rsum[m] += (p0 + p1) + (p2 + p3);
            uint2 pk;
            pk.x = cvt_pk_bf16(p0, p1);
            pk.y = cvt_pk_bf16(p2, p3);
            *(uint2*)&P[wave][l16][nt * 16 + quad * 4] = pk;
          }
        } else {  // diagonal tile: mask kv > qi (qi = qb + l16)
          int qi = qb + l16;
#pragma unroll
          for (int nt = 0; nt < 4; nt++) {
            int kvb = kv0 + nt * 16 + quad * 4;
            float pv[4];
#pragma unroll
            for (int r = 0; r < 4; r++)
              pv[r] = (kvb + r <= qi) ? __builtin_amdgcn_exp2f(fmaf(s[nt][r], EXP2SCALE, -EXP2OFF)) : 0.f;
            rsum[m] += (pv[0] + pv[1]) + (pv[2] + pv[3]);
            uint2 pk;
            pk.x = cvt_pk_bf16(pv[0], pv[1]);
            pk.y = cvt_pk_bf16(pv[2], pv[3]);
            *(uint2*)&P[wave][l16][nt * 16 + quad * 4] = pk;
          }
        }
        s16x8 ap0 = *(const s16x8*)&P[wave][l16][quad * 8];
        s16x8 ap1 = *(const s16x8*)&P[wave][l16][32 + quad * 8];
#pragma unroll
        for (int dt = 0; dt < 4; dt++) {
          o[m][dt] = __builtin_amdgcn_mfma_f32_16x16x32_bf16(ap0, bv[dt][0], o[m][dt], 0, 0, 0);
          o[m][dt] = __builtin_amdgcn_mfma_f32_16x16x32_bf16(ap1, bv[dt][1], o[m][dt], 0, 0, 0);
        }
      }
    }
  }
  // rsum[m] holds this lane's partial (quad's kv slice) for q = l16.
  // Reduce across quads -> every lane has the full sum for its l16.
#pragma unroll
  for (int m = 0; m < 2; m++) {
    rsum[m] += __shfl_xor(rsum[m], 16);
    rsum[m] += __shfl_xor(rsum[m], 32);
  }
#pragma unroll
  for (int m = 0; m < 2; m++)
#pragma unroll
    for (int r = 0; r < 4; r++) {
      float inv = 1.0f / __shfl(rsum[m], quad * 4 + r);  // lane (quad*4+r) holds q-sub = quad*4+r
      int q = qbase0 + m * 16 + quad * 4 + r;
#pragma unroll
      for (int dt = 0; dt < 4; dt++)
        Ob[(size_t)(b * T_ + q) * DM + h * 64 + dt * 16 + l16] = f2b(o[m][dt][r] * inv);
    }
}

extern "C" void kernel_launch(void* const* d_in, const int* in_sizes, int n_in,
                              void* d_out, int out_size, void* d_ws, size_t ws_size,
                              hipStream_t stream) {
  const float* x = (const float*)d_in[0];
  const float* rc = (const float*)d_in[1];
  const float* rs = (const float*)d_in[2];
  const float* wq = (const float*)d_in[3];
  const float* wk = (const float*)d_in[4];
  const float* wv = (const float*)d_in[5];
  const float* wo = (const float*)d_in[6];

  char* ws = (char*)d_ws;
  ushort* xb   = (ushort*)(ws);                 // 12,582,912
  ushort* wqkv = (ushort*)(ws + 12582912);      //  3,538,944
  ushort* wob  = (ushort*)(ws + 16121856);      //  1,179,648
  float2* cs2  = (float2*)(ws + 17301504);      //    524,288
  ushort* Qb   = (ushort*)(ws + 17825792);      // 12,582,912
  ushort* Kb   = (ushort*)(ws + 30408704);      // 12,582,912
  ushort* Vt   = (ushort*)(ws + 42991616);      // 12,582,912
  ushort* Ob   = (ushort*)(ws + 55574528);      // 12,582,912 (ends ~68.2MB)

  cvt_all<<<8704, 256, 0, stream>>>(x, wq, wk, wv, wo, rc, rs, xb, wqkv, wob, cs2);

  gemm_qkv<<<1152, 256, 0, stream>>>(xb, wqkv, cs2, Qb, Kb, Vt);

  attn<<<dim3(48, 16), 256, 0, stream>>>(Qb, Kb, Vt, Ob);

  gemm_out<<<384, 256, 0, stream>>>(Ob, wob, (float*)d_out);
}